// Round 14
// baseline (494.757 us; speedup 1.0000x reference)
//
#include <hip/hip_runtime.h>

// ---------------------------------------------------------------------------
// ProteinGCNNet: 3x GCNConv + mean-pool + 2 FC layers.
// Round 14: launch-graph consolidation (23 -> 14 kernels). CSR build is now
// hist -> part -> build (per-bucket hist+scan+rowptr+dinv+fill in one kernel,
// with redundant in-block scans of the 256-entry bucket table instead of
// separate scan launches). FC head fused into one kernel. MFMA GEMMs,
// fp16 gathers (at L3-fabric roofline ~3.5 TB/s), fused pool kept.
// ---------------------------------------------------------------------------

typedef _Float16 f16;
typedef _Float16 f16x2 __attribute__((ext_vector_type(2)));
typedef _Float16 f16x8 __attribute__((ext_vector_type(8)));
typedef float f32x4 __attribute__((ext_vector_type(4)));

static __host__ __device__ inline int cdiv(int a, int b) { return (a + b - 1) / b; }

constexpr int BSPAN = 512;
constexpr int EPB   = 4096;
constexpr int EPT   = EPB / 256;

template <int V>
__device__ __forceinline__ void vload(float* d, const float* s) {
    if constexpr (V == 1) { d[0] = s[0]; }
    else if constexpr (V == 2) { float2 t = *reinterpret_cast<const float2*>(s); d[0] = t.x; d[1] = t.y; }
    else { float4 t = *reinterpret_cast<const float4*>(s); d[0] = t.x; d[1] = t.y; d[2] = t.z; d[3] = t.w; }
}

// ---- combined MFMA weight pack (3 tensors, one launch) ---------------------
__device__ __forceinline__ void wpack_one(const float* W, f16* Wb, int K, int F,
                                          int KT, int idx) {
    int j = idx & 7;
    int lane = (idx >> 3) & 63;
    int fi = idx >> 9;
    int kt = fi % KT;
    int nt = fi / KT;
    int k = kt * 32 + (lane >> 4) * 8 + j;
    int nn = nt * 16 + (lane & 15);
    Wb[idx] = (k < K && nn < F) ? (f16)W[k * F + nn] : (f16)0.f;
}
__global__ void k_wpack3(const float* __restrict__ W1, const float* __restrict__ W2,
                         const float* __restrict__ W3, f16* __restrict__ w1b,
                         f16* __restrict__ w2b, f16* __restrict__ w3b) {
    constexpr int T1 = 4 * 2 * 512;    // 54->54:  NT=4,  KT=2
    constexpr int T2 = 7 * 2 * 512;    // 54->108: NT=7,  KT=2
    constexpr int T3 = 14 * 4 * 512;   // 108->216: NT=14, KT=4
    int idx = blockIdx.x * blockDim.x + threadIdx.x;
    if (idx < T1) wpack_one(W1, w1b, 54, 54, 2, idx);
    else if (idx < T1 + T2) wpack_one(W2, w2b, 54, 108, 2, idx - T1);
    else if (idx < T1 + T2 + T3) wpack_one(W3, w3b, 108, 216, 4, idx - T1 - T2);
}

// ---- setup: zero psum + bktCnt + bktCur ------------------------------------
__global__ void k_setup(float* psum, int nf, int* bktCnt, int* bktCur) {
    int i = blockIdx.x * blockDim.x + threadIdx.x;
    if (i < nf) psum[i] = 0.f;
    if (i < 256) { bktCnt[i] = 0; bktCur[i] = 0; }
}

// ---- A1: per-block LDS bucket histogram ------------------------------------
__global__ __launch_bounds__(256) void k_bkt_hist(const int* __restrict__ col,
                                                  int* bktCnt, int e, int nb) {
    __shared__ int hist[256];
    int t = threadIdx.x;
    hist[t] = 0;
    __syncthreads();
    int base = blockIdx.x * EPB;
#pragma unroll
    for (int j = 0; j < EPT; j++) {
        int idx = base + j * 256 + t;
        if (idx < e) atomicAdd(&hist[col[idx] >> 9], 1);
    }
    __syncthreads();
    if (t < nb && hist[t] > 0) atomicAdd(&bktCnt[t], hist[t]);
}

// ---- in-block exclusive scan of bktCnt (sbuf holds inclusive after) --------
__device__ __forceinline__ int scan256_ex(int* sbuf, int v, int t) {
    sbuf[t] = v;
    __syncthreads();
    for (int off = 1; off < 256; off <<= 1) {
        int x = sbuf[t];
        int y = (t >= off) ? sbuf[t - off] : 0;
        __syncthreads();
        sbuf[t] = x + y;
        __syncthreads();
    }
    return sbuf[t] - v;
}

// ---- A2: partition edges into bucket-contiguous (col,row) pairs ------------
// Computes bktOff in-block (scan of bktCnt); bktCur is a zeroed global cursor.
__global__ __launch_bounds__(256) void k_bkt_part(const int* __restrict__ row,
                                                  const int* __restrict__ col,
                                                  const int* __restrict__ bktCnt,
                                                  int* bktCur, int2* __restrict__ ebuf,
                                                  int e, int nb) {
    __shared__ int sbuf[256];
    __shared__ int hist[256];
    __shared__ int base[256];
    __shared__ int lcur[256];
    int t = threadIdx.x;
    int boff = scan256_ex(sbuf, (t < nb) ? bktCnt[t] : 0, t);
    hist[t] = 0; lcur[t] = 0;
    __syncthreads();
    int bs = blockIdx.x * EPB;
    int r[EPT], c[EPT], b[EPT];
#pragma unroll
    for (int j = 0; j < EPT; j++) {
        int idx = bs + j * 256 + t;
        if (idx < e) {
            c[j] = col[idx]; r[j] = row[idx]; b[j] = c[j] >> 9;
            atomicAdd(&hist[b[j]], 1);
        } else b[j] = -1;
    }
    __syncthreads();
    if (t < nb && hist[t] > 0) base[t] = boff + atomicAdd(&bktCur[t], hist[t]);
    __syncthreads();
#pragma unroll
    for (int j = 0; j < EPT; j++) {
        if (b[j] >= 0) {
            int lofs = atomicAdd(&lcur[b[j]], 1);
            ebuf[base[b[j]] + lofs] = make_int2(c[j], r[j]);
        }
    }
}

// ---- B: per-bucket hist + scan -> rowptr + dinv + CSR fill (one kernel) ----
__global__ __launch_bounds__(256) void k_bkt_build(const int2* __restrict__ ebuf,
                                                   const int* __restrict__ bktCnt,
                                                   int* __restrict__ rowptr,
                                                   float* __restrict__ dinv,
                                                   int* __restrict__ eSrc,
                                                   int n, int nb) {
    __shared__ int sbuf[256];
    __shared__ int hist[BSPAN];
    __shared__ int cur[BSPAN];
    int t = threadIdx.x;
    int bkt = blockIdx.x;

    // bucket offset = exclusive scan of bktCnt at index bkt
    int boff_ex = scan256_ex(sbuf, (t < nb) ? bktCnt[t] : 0, t);
    __shared__ int boff_s, cnt_s;
    if (t == bkt) { boff_s = boff_ex; }
    if (t == 0) cnt_s = bktCnt[bkt];
    hist[t] = 0; hist[t + 256] = 0;
    __syncthreads();
    int es = boff_s, ee = boff_s + cnt_s;

    // local histogram over this bucket's 512 nodes
    for (int i = es + t; i < ee; i += 256)
        atomicAdd(&hist[ebuf[i].x & (BSPAN - 1)], 1);
    __syncthreads();

    // 512-entry exclusive scan (pairwise + 256-scan)
    int h0 = hist[2 * t], h1 = hist[2 * t + 1];
    __syncthreads();
    int ex = scan256_ex(sbuf, h0 + h1, t);
    int e0 = es + ex, e1 = e0 + h0;

    int node0 = bkt * BSPAN;
    int n0 = node0 + 2 * t, n1 = node0 + 2 * t + 1;
    if (n0 <= n) rowptr[n0] = e0;
    if (n1 <= n) rowptr[n1] = e1;
    if (n0 < n) dinv[n0] = rsqrtf((float)(h0 + 1));
    if (n1 < n) dinv[n1] = rsqrtf((float)(h1 + 1));
    cur[2 * t] = e0; cur[2 * t + 1] = e1;
    __syncthreads();

    // fill (single-CU-local writes into [es, ee))
    for (int i = es + t; i < ee; i += 256) {
        int2 p = ebuf[i];
        int slot = atomicAdd(&cur[p.x & (BSPAN - 1)], 1);
        eSrc[slot] = p.y;
    }
}

// ---- xs = f16(dinv (x) x) ---------------------------------------------------
template <int F>
__global__ void k_prescale(const float* __restrict__ x, const float* __restrict__ dinv,
                           f16* __restrict__ xs, int n) {
    constexpr int CH = F / 2;
    int idx = blockIdx.x * blockDim.x + threadIdx.x;
    if (idx >= n * CH) return;
    int node = idx / CH;
    int c = idx - node * CH;
    float d = dinv[node];
    float v[2];
    vload<2>(v, x + (long long)node * F + c * 2);
    f16x2 h;
    h[0] = (f16)(v[0] * d);
    h[1] = (f16)(v[1] * d);
    *reinterpret_cast<f16x2*>(xs + (long long)node * F + c * 2) = h;
}

// ---- per-graph boundaries (batch sorted ascending; self-initializing) ------
__global__ void k_find_start(const int* __restrict__ batch, int* start, int n, int g) {
    int i = blockIdx.x * blockDim.x + threadIdx.x;
    if (i >= n) return;
    int b = batch[i];
    int bp = (i == 0) ? -1 : batch[i - 1];
    for (int gg = bp + 1; gg <= b; gg++) start[gg] = i;
    if (i == n - 1)
        for (int gg = b + 1; gg <= g; gg++) start[gg] = n;
}

// ---- gather row-sum (fp16 in, fp32 accum, fp16 out) ------------------------
template <int F>
__global__ __launch_bounds__(256) void k_gather(
        const int* __restrict__ rowptr, const int* __restrict__ eSrc,
        const float* __restrict__ dinv, const f16* __restrict__ hs,
        f16* __restrict__ out, int n) {
    constexpr int CH = F / 2;
    int wave = threadIdx.x >> 6;
    int lane = threadIdx.x & 63;
    int node = blockIdx.x * (blockDim.x >> 6) + wave;
    if (node >= n || lane >= CH) return;

    f16x2 sv = *reinterpret_cast<const f16x2*>(hs + (long long)node * F + lane * 2);
    float acc0 = (float)sv[0], acc1 = (float)sv[1];

    int rs = rowptr[node], re = rowptr[node + 1];
    int e = rs;
    for (; e + 8 <= re; e += 8) {
        int s[8];
#pragma unroll
        for (int u = 0; u < 8; u++) s[u] = eSrc[e + u];
        f16x2 v[8];
#pragma unroll
        for (int u = 0; u < 8; u++)
            v[u] = *reinterpret_cast<const f16x2*>(hs + (long long)s[u] * F + lane * 2);
#pragma unroll
        for (int u = 0; u < 8; u++) {
            acc0 += (float)v[u][0];
            acc1 += (float)v[u][1];
        }
    }
    for (; e < re; e++) {
        int s = eSrc[e];
        f16x2 v = *reinterpret_cast<const f16x2*>(hs + (long long)s * F + lane * 2);
        acc0 += (float)v[0];
        acc1 += (float)v[1];
    }
    float di = dinv[node];
    f16x2 o;
    o[0] = (f16)(acc0 * di);
    o[1] = (f16)(acc1 * di);
    *reinterpret_cast<f16x2*>(out + (long long)node * F + lane * 2) = o;
}

// ---- MFMA node GEMM (Block = 4 waves x 64 nodes) ---------------------------
template <int KTILES, int NTILES, int K, int FOUT, bool POOL>
__global__ __launch_bounds__(256) void k_gemm_mfma(
        const f16* __restrict__ in, const f16* __restrict__ Wb,
        const float* __restrict__ bias, const float* __restrict__ dinv,
        const int* __restrict__ batch, f16* __restrict__ outh,
        float* __restrict__ psum, int n) {
    constexpr int KPAD = KTILES * 32;
    constexpr int KP   = KPAD + 8;
    constexpr int PPR  = KPAD / 2;
    constexpr int NSLOT = 4;

    __shared__ f16 a_lds[64 * KP];
    __shared__ float psum_l[POOL ? NSLOT * FOUT : 1];

    int t = threadIdx.x;
    int node0 = blockIdx.x * 64;

    const f16x2* inp = reinterpret_cast<const f16x2*>(in);
    constexpr int TOTP = 64 * PPR;
    for (int f = t; f < TOTP; f += 256) {
        int node = f / PPR;
        int kp = f - node * PPR;
        f16x2 v = {};
        if (node0 + node < n && kp < K / 2)
            v = inp[(long long)(node0 + node) * (K / 2) + kp];
        *reinterpret_cast<f16x2*>(&a_lds[node * KP + kp * 2]) = v;
    }
    if (POOL) {
        for (int i = t; i < NSLOT * FOUT; i += 256) psum_l[i] = 0.f;
    }
    __syncthreads();

    int w = t >> 6;
    int lane = t & 63;
    int quad = lane >> 4;
    int col = lane & 15;

    f16x8 afr[KTILES];
#pragma unroll
    for (int kt = 0; kt < KTILES; kt++)
        afr[kt] = *reinterpret_cast<const f16x8*>(
            &a_lds[(16 * w + col) * KP + kt * 32 + quad * 8]);

    int nodeC = node0 + 16 * w + quad * 4;
    float dv[4];
    int gb[4];
#pragma unroll
    for (int r = 0; r < 4; r++) {
        int nd = nodeC + r;
        bool valid = nd < n;
        if (POOL) {
            gb[r] = valid ? batch[nd] : -1;
            dv[r] = 0.f;
        } else {
            dv[r] = valid ? dinv[nd] : 0.f;
            gb[r] = -1;
        }
    }
    int g0 = POOL ? batch[node0] : 0;

    const f16x8* wb = reinterpret_cast<const f16x8*>(Wb);
#pragma unroll
    for (int nt = 0; nt < NTILES; nt++) {
        f16x8 bfr[KTILES];
#pragma unroll
        for (int kt = 0; kt < KTILES; kt++)
            bfr[kt] = wb[(nt * KTILES + kt) * 64 + lane];
        f32x4 acc = {0.f, 0.f, 0.f, 0.f};
#pragma unroll
        for (int kt = 0; kt < KTILES; kt++)
            acc = __builtin_amdgcn_mfma_f32_16x16x32_f16(afr[kt], bfr[kt], acc, 0, 0, 0);

        int ch = nt * 16 + col;
        if (ch < FOUT) {
            float bval = bias[ch];
            if (POOL) {
                if (gb[0] == gb[3] && gb[0] >= 0) {
                    float s = fmaxf(acc[0] + bval, 0.f) + fmaxf(acc[1] + bval, 0.f)
                            + fmaxf(acc[2] + bval, 0.f) + fmaxf(acc[3] + bval, 0.f);
                    int slot = gb[0] - g0;
                    if (slot < NSLOT) atomicAdd(&psum_l[slot * FOUT + ch], s);
                    else atomicAdd(&psum[gb[0] * FOUT + ch], s);
                } else {
#pragma unroll
                    for (int r = 0; r < 4; r++) {
                        if (gb[r] < 0) continue;
                        float v = fmaxf(acc[r] + bval, 0.f);
                        int slot = gb[r] - g0;
                        if (slot < NSLOT) atomicAdd(&psum_l[slot * FOUT + ch], v);
                        else atomicAdd(&psum[gb[r] * FOUT + ch], v);
                    }
                }
            } else {
#pragma unroll
                for (int r = 0; r < 4; r++) {
                    int nd = nodeC + r;
                    if (nd < n)
                        outh[(long long)nd * FOUT + ch] =
                            (f16)(fmaxf(acc[r] + bval, 0.f) * dv[r]);
                }
            }
        }
    }

    if (POOL) {
        __syncthreads();
        int lastNode = node0 + 63;
        if (lastNode >= n) lastNode = n - 1;
        int nsl = batch[lastNode] - g0 + 1;
        if (nsl > NSLOT) nsl = NSLOT;
        for (int f = t; f < nsl * FOUT; f += 256) {
            float v = psum_l[f];
            if (v != 0.f) atomicAdd(&psum[(g0 + f / FOUT) * FOUT + (f % FOUT)], v);
        }
    }
}

// ---- fused FC head: out = (relu(pooled @ Wf1 + bf1)) @ Wf2 + bf2 -----------
__global__ __launch_bounds__(256) void k_fc(const float* __restrict__ P,
                                            const int* __restrict__ start,
                                            const float* __restrict__ Wf1,
                                            const float* __restrict__ bf1,
                                            const float* __restrict__ Wf2,
                                            const float* __restrict__ bf2,
                                            float* __restrict__ out) {
    __shared__ float prow[216];
    __shared__ float g_l[1024];
    int row = blockIdx.x;
    int t = threadIdx.x;
    int cnt = start[row + 1] - start[row];
    float scale = 1.0f / fmaxf((float)cnt, 1.0f);
    if (t < 216) prow[t] = P[row * 216 + t] * scale;
    __syncthreads();
    for (int o = t; o < 1024; o += 256) {
        float acc = bf1[o];
        for (int k = 0; k < 216; k++) acc += prow[k] * Wf1[k * 1024 + o];
        g_l[o] = fmaxf(acc, 0.f);
    }
    __syncthreads();
    if (t < 128) {
        float acc = bf2[t];
        for (int k = 0; k < 1024; k++) acc += g_l[k] * Wf2[k * 128 + t];
        out[row * 128 + t] = acc;
    }
}

// ---------------------------------------------------------------------------
extern "C" void kernel_launch(void* const* d_in, const int* in_sizes, int n_in,
                              void* d_out, int out_size, void* d_ws, size_t ws_size,
                              hipStream_t stream) {
    const float* x     = (const float*)d_in[0];
    const int*   ei    = (const int*)d_in[1];
    const int*   batch = (const int*)d_in[2];
    const float* W1  = (const float*)d_in[3];
    const float* b1  = (const float*)d_in[4];
    const float* W2  = (const float*)d_in[5];
    const float* b2  = (const float*)d_in[6];
    const float* W3  = (const float*)d_in[7];
    const float* b3  = (const float*)d_in[8];
    const float* Wf1 = (const float*)d_in[9];
    const float* bf1 = (const float*)d_in[10];
    const float* Wf2 = (const float*)d_in[11];
    const float* bf2 = (const float*)d_in[12];
    float* out = (float*)d_out;

    const int N = in_sizes[0] / 54;   // 100000
    const int E = in_sizes[1] / 2;    // 1600000
    const int G = 256;
    const int* row = ei;
    const int* col = ei + E;
    const int NB = cdiv(N, BSPAN);    // 196
    const int NBLK_A = cdiv(E, EPB);

    // workspace carve-up (256B aligned)
    char* ws = (char*)d_ws;
    size_t off = 0;
    auto carve = [&](size_t bytes) {
        void* p = ws + off;
        off += (bytes + 255) & ~(size_t)255;
        return p;
    };
    int*   rowptr  = (int*)carve((size_t)(N + 1) * 4);
    int*   bktCnt  = (int*)carve(256 * 4);
    int*   bktCur  = (int*)carve(256 * 4);
    int*   eSrc    = (int*)carve((size_t)E * 4);
    float* dinv    = (float*)carve((size_t)N * 4);
    f16*   xs      = (f16*)carve((size_t)N * 54 * 2);
    f16*   hsbuf   = (f16*)carve((size_t)N * 108 * 2);
    f16*   bufA    = (f16*)carve((size_t)N * 108 * 2);
    int2*  ebuf    = (int2*)carve((size_t)E * 8);
    float* psum    = (float*)carve((size_t)G * 216 * 4);
    int*   start   = (int*)carve((size_t)(G + 1) * 4);
    f16*   w1b     = (f16*)carve((size_t)4 * 2 * 512 * 2);
    f16*   w2b     = (f16*)carve((size_t)7 * 2 * 512 * 2);
    f16*   w3b     = (f16*)carve((size_t)14 * 4 * 512 * 2);

    const int T = 256;

    // ---- setup + weight pack (independent of edge data) ----
    k_setup<<<cdiv(G * 216, T), T, 0, stream>>>(psum, G * 216, bktCnt, bktCur);
    k_wpack3<<<cdiv((4 * 2 + 7 * 2 + 14 * 4) * 512, T), T, 0, stream>>>(
        W1, W2, W3, w1b, w2b, w3b);

    // ---- bucketed CSR build: hist -> part -> build ----
    k_bkt_hist<<<NBLK_A, 256, 0, stream>>>(col, bktCnt, E, NB);
    k_bkt_part<<<NBLK_A, 256, 0, stream>>>(row, col, bktCnt, bktCur, ebuf, E, NB);
    k_bkt_build<<<NB, 256, 0, stream>>>(ebuf, bktCnt, rowptr, dinv, eSrc, N, NB);

    // ---- prescale + graph boundaries ----
    k_prescale<54><<<cdiv(N * 27, T), T, 0, stream>>>(x, dinv, xs, N);
    k_find_start<<<cdiv(N, T), T, 0, stream>>>(batch, start, N, G);

    const int GB = cdiv(N, 64);

    // ---- layer 1 ----
    k_gather<54><<<cdiv(N, 4), 256, 0, stream>>>(rowptr, eSrc, dinv, xs, bufA, N);
    k_gemm_mfma<2, 4, 54, 54, false><<<GB, 256, 0, stream>>>(
        bufA, w1b, b1, dinv, nullptr, hsbuf, nullptr, N);

    // ---- layer 2 ----
    k_gather<54><<<cdiv(N, 4), 256, 0, stream>>>(rowptr, eSrc, dinv, hsbuf, bufA, N);
    k_gemm_mfma<2, 7, 54, 108, false><<<GB, 256, 0, stream>>>(
        bufA, w2b, b2, dinv, nullptr, hsbuf, nullptr, N);

    // ---- layer 3 (fused pool) ----
    k_gather<108><<<cdiv(N, 4), 256, 0, stream>>>(rowptr, eSrc, dinv, hsbuf, bufA, N);
    k_gemm_mfma<4, 14, 108, 216, true><<<GB, 256, 0, stream>>>(
        bufA, w3b, b3, nullptr, batch, nullptr, psum, N);

    // ---- fused FC head ----
    k_fc<<<G, 256, 0, stream>>>(psum, start, Wf1, bf1, Wf2, bf2, out);
}

// Round 15
// 455.977 us; speedup vs baseline: 1.0850x; 1.0850x over previous
//
#include <hip/hip_runtime.h>

// ---------------------------------------------------------------------------
// ProteinGCNNet: 3x GCNConv + mean-pool + 2 FC layers.
// Round 15: (1) dual-edge gather for F=54 (idle lanes 32-58 process edge e+1,
// shfl-combine halves -> ~2x request rate), (2) ebuf packed to int32
// ((ldst<<17)|src, N<2^17), (3) FC head un-fused (round-14 regression).
// MFMA GEMMs, fused pool, bucketed CSR kept.
// ---------------------------------------------------------------------------

typedef _Float16 f16;
typedef _Float16 f16x2 __attribute__((ext_vector_type(2)));
typedef _Float16 f16x8 __attribute__((ext_vector_type(8)));
typedef float f32x4 __attribute__((ext_vector_type(4)));

static __host__ __device__ inline int cdiv(int a, int b) { return (a + b - 1) / b; }

constexpr int BSPAN = 512;
constexpr int EPB   = 4096;
constexpr int EPT   = EPB / 256;

template <int V>
__device__ __forceinline__ void vload(float* d, const float* s) {
    if constexpr (V == 1) { d[0] = s[0]; }
    else if constexpr (V == 2) { float2 t = *reinterpret_cast<const float2*>(s); d[0] = t.x; d[1] = t.y; }
    else { float4 t = *reinterpret_cast<const float4*>(s); d[0] = t.x; d[1] = t.y; d[2] = t.z; d[3] = t.w; }
}

// ---- combined MFMA weight pack (3 tensors, one launch) ---------------------
__device__ __forceinline__ void wpack_one(const float* W, f16* Wb, int K, int F,
                                          int KT, int idx) {
    int j = idx & 7;
    int lane = (idx >> 3) & 63;
    int fi = idx >> 9;
    int kt = fi % KT;
    int nt = fi / KT;
    int k = kt * 32 + (lane >> 4) * 8 + j;
    int nn = nt * 16 + (lane & 15);
    Wb[idx] = (k < K && nn < F) ? (f16)W[k * F + nn] : (f16)0.f;
}
__global__ void k_wpack3(const float* __restrict__ W1, const float* __restrict__ W2,
                         const float* __restrict__ W3, f16* __restrict__ w1b,
                         f16* __restrict__ w2b, f16* __restrict__ w3b) {
    constexpr int T1 = 4 * 2 * 512;
    constexpr int T2 = 7 * 2 * 512;
    constexpr int T3 = 14 * 4 * 512;
    int idx = blockIdx.x * blockDim.x + threadIdx.x;
    if (idx < T1) wpack_one(W1, w1b, 54, 54, 2, idx);
    else if (idx < T1 + T2) wpack_one(W2, w2b, 54, 108, 2, idx - T1);
    else if (idx < T1 + T2 + T3) wpack_one(W3, w3b, 108, 216, 4, idx - T1 - T2);
}

// ---- setup: zero psum + bktCnt + bktCur ------------------------------------
__global__ void k_setup(float* psum, int nf, int* bktCnt, int* bktCur) {
    int i = blockIdx.x * blockDim.x + threadIdx.x;
    if (i < nf) psum[i] = 0.f;
    if (i < 256) { bktCnt[i] = 0; bktCur[i] = 0; }
}

// ---- A1: per-block LDS bucket histogram ------------------------------------
__global__ __launch_bounds__(256) void k_bkt_hist(const int* __restrict__ col,
                                                  int* bktCnt, int e, int nb) {
    __shared__ int hist[256];
    int t = threadIdx.x;
    hist[t] = 0;
    __syncthreads();
    int base = blockIdx.x * EPB;
#pragma unroll
    for (int j = 0; j < EPT; j++) {
        int idx = base + j * 256 + t;
        if (idx < e) atomicAdd(&hist[col[idx] >> 9], 1);
    }
    __syncthreads();
    if (t < nb && hist[t] > 0) atomicAdd(&bktCnt[t], hist[t]);
}

// ---- in-block exclusive scan ------------------------------------------------
__device__ __forceinline__ int scan256_ex(int* sbuf, int v, int t) {
    sbuf[t] = v;
    __syncthreads();
    for (int off = 1; off < 256; off <<= 1) {
        int x = sbuf[t];
        int y = (t >= off) ? sbuf[t - off] : 0;
        __syncthreads();
        sbuf[t] = x + y;
        __syncthreads();
    }
    return sbuf[t] - v;
}

// ---- A2: partition edges; ebuf packed (ldst<<17)|src (N < 2^17) ------------
__global__ __launch_bounds__(256) void k_bkt_part(const int* __restrict__ row,
                                                  const int* __restrict__ col,
                                                  const int* __restrict__ bktCnt,
                                                  int* bktCur, unsigned int* __restrict__ ebuf,
                                                  int e, int nb) {
    __shared__ int sbuf[256];
    __shared__ int hist[256];
    __shared__ int base[256];
    __shared__ int lcur[256];
    int t = threadIdx.x;
    int boff = scan256_ex(sbuf, (t < nb) ? bktCnt[t] : 0, t);
    hist[t] = 0; lcur[t] = 0;
    __syncthreads();
    int bs = blockIdx.x * EPB;
    unsigned int pk[EPT];
    int b[EPT];
#pragma unroll
    for (int j = 0; j < EPT; j++) {
        int idx = bs + j * 256 + t;
        if (idx < e) {
            int c = col[idx];
            pk[j] = ((unsigned int)(c & (BSPAN - 1)) << 17) | (unsigned int)row[idx];
            b[j] = c >> 9;
            atomicAdd(&hist[b[j]], 1);
        } else b[j] = -1;
    }
    __syncthreads();
    if (t < nb && hist[t] > 0) base[t] = boff + atomicAdd(&bktCur[t], hist[t]);
    __syncthreads();
#pragma unroll
    for (int j = 0; j < EPT; j++) {
        if (b[j] >= 0) {
            int lofs = atomicAdd(&lcur[b[j]], 1);
            ebuf[base[b[j]] + lofs] = pk[j];
        }
    }
}

// ---- B: per-bucket hist+scan -> rowptr + dinv + CSR fill -------------------
__global__ __launch_bounds__(256) void k_bkt_build(const unsigned int* __restrict__ ebuf,
                                                   const int* __restrict__ bktCnt,
                                                   int* __restrict__ rowptr,
                                                   float* __restrict__ dinv,
                                                   int* __restrict__ eSrc,
                                                   int n, int nb) {
    __shared__ int sbuf[256];
    __shared__ int hist[BSPAN];
    __shared__ int cur[BSPAN];
    int t = threadIdx.x;
    int bkt = blockIdx.x;

    int boff_ex = scan256_ex(sbuf, (t < nb) ? bktCnt[t] : 0, t);
    __shared__ int boff_s, cnt_s;
    if (t == bkt) boff_s = boff_ex;
    if (t == 0) cnt_s = bktCnt[bkt];
    hist[t] = 0; hist[t + 256] = 0;
    __syncthreads();
    int es = boff_s, ee = boff_s + cnt_s;

    for (int i = es + t; i < ee; i += 256)
        atomicAdd(&hist[ebuf[i] >> 17], 1);
    __syncthreads();

    int h0 = hist[2 * t], h1 = hist[2 * t + 1];
    __syncthreads();
    int ex = scan256_ex(sbuf, h0 + h1, t);
    int e0 = es + ex, e1 = e0 + h0;

    int node0 = bkt * BSPAN;
    int n0 = node0 + 2 * t, n1 = node0 + 2 * t + 1;
    if (n0 <= n) rowptr[n0] = e0;
    if (n1 <= n) rowptr[n1] = e1;
    if (n0 < n) dinv[n0] = rsqrtf((float)(h0 + 1));
    if (n1 < n) dinv[n1] = rsqrtf((float)(h1 + 1));
    cur[2 * t] = e0; cur[2 * t + 1] = e1;
    __syncthreads();

    for (int i = es + t; i < ee; i += 256) {
        unsigned int p = ebuf[i];
        int slot = atomicAdd(&cur[p >> 17], 1);
        eSrc[slot] = (int)(p & 0x1FFFFu);
    }
}

// ---- xs = f16(dinv (x) x) ---------------------------------------------------
template <int F>
__global__ void k_prescale(const float* __restrict__ x, const float* __restrict__ dinv,
                           f16* __restrict__ xs, int n) {
    constexpr int CH = F / 2;
    int idx = blockIdx.x * blockDim.x + threadIdx.x;
    if (idx >= n * CH) return;
    int node = idx / CH;
    int c = idx - node * CH;
    float d = dinv[node];
    float v[2];
    vload<2>(v, x + (long long)node * F + c * 2);
    f16x2 h;
    h[0] = (f16)(v[0] * d);
    h[1] = (f16)(v[1] * d);
    *reinterpret_cast<f16x2*>(xs + (long long)node * F + c * 2) = h;
}

// ---- per-graph boundaries (batch sorted; self-initializing) ----------------
__global__ void k_find_start(const int* __restrict__ batch, int* start, int n, int g) {
    int i = blockIdx.x * blockDim.x + threadIdx.x;
    if (i >= n) return;
    int b = batch[i];
    int bp = (i == 0) ? -1 : batch[i - 1];
    for (int gg = bp + 1; gg <= b; gg++) start[gg] = i;
    if (i == n - 1)
        for (int gg = b + 1; gg <= g; gg++) start[gg] = n;
}

// ---- dual-edge gather for F=54: lanes 0-26 edge e, lanes 32-58 edge e+1 ----
// out[i] = f16(dinv[i] * (hs[i] + sum_s hs[s]))
__global__ __launch_bounds__(256) void k_gather54(
        const int* __restrict__ rowptr, const int* __restrict__ eSrc,
        const float* __restrict__ dinv, const f16* __restrict__ hs,
        f16* __restrict__ out, int n) {
    constexpr int F = 54, CH = 27;
    int wave = threadIdx.x >> 6;
    int lane = threadIdx.x & 63;
    int half = lane >> 5;
    int l = lane & 31;
    int node = blockIdx.x * (blockDim.x >> 6) + wave;
    if (node >= n) return;
    bool act = l < CH;

    float acc0 = 0.f, acc1 = 0.f;
    if (half == 0 && act) {
        f16x2 sv = *reinterpret_cast<const f16x2*>(hs + (long long)node * F + l * 2);
        acc0 = (float)sv[0]; acc1 = (float)sv[1];
    }

    int rs = rowptr[node], re = rowptr[node + 1];
    int e = rs + half;
    // 4 edges per half per iteration (8 total in flight per wave)
    for (; e + 6 < re; e += 8) {
        int s0 = eSrc[e], s1 = eSrc[e + 2], s2 = eSrc[e + 4], s3 = eSrc[e + 6];
        if (act) {
            f16x2 v0 = *reinterpret_cast<const f16x2*>(hs + (long long)s0 * F + l * 2);
            f16x2 v1 = *reinterpret_cast<const f16x2*>(hs + (long long)s1 * F + l * 2);
            f16x2 v2 = *reinterpret_cast<const f16x2*>(hs + (long long)s2 * F + l * 2);
            f16x2 v3 = *reinterpret_cast<const f16x2*>(hs + (long long)s3 * F + l * 2);
            acc0 += (float)v0[0] + (float)v1[0] + (float)v2[0] + (float)v3[0];
            acc1 += (float)v0[1] + (float)v1[1] + (float)v2[1] + (float)v3[1];
        }
    }
    for (; e < re; e += 2) {
        int s = eSrc[e];
        if (act) {
            f16x2 v = *reinterpret_cast<const f16x2*>(hs + (long long)s * F + l * 2);
            acc0 += (float)v[0];
            acc1 += (float)v[1];
        }
    }
    // combine halves (lane ^ 32)
    acc0 += __shfl_xor(acc0, 32);
    acc1 += __shfl_xor(acc1, 32);

    if (half == 0 && act) {
        float di = dinv[node];
        f16x2 o;
        o[0] = (f16)(acc0 * di);
        o[1] = (f16)(acc1 * di);
        *reinterpret_cast<f16x2*>(out + (long long)node * F + l * 2) = o;
    }
}

// ---- gather row-sum F=108 (fp16 in, fp32 accum, fp16 out) ------------------
template <int F>
__global__ __launch_bounds__(256) void k_gather(
        const int* __restrict__ rowptr, const int* __restrict__ eSrc,
        const float* __restrict__ dinv, const f16* __restrict__ hs,
        f16* __restrict__ out, int n) {
    constexpr int CH = F / 2;
    int wave = threadIdx.x >> 6;
    int lane = threadIdx.x & 63;
    int node = blockIdx.x * (blockDim.x >> 6) + wave;
    if (node >= n || lane >= CH) return;

    f16x2 sv = *reinterpret_cast<const f16x2*>(hs + (long long)node * F + lane * 2);
    float acc0 = (float)sv[0], acc1 = (float)sv[1];

    int rs = rowptr[node], re = rowptr[node + 1];
    int e = rs;
    for (; e + 8 <= re; e += 8) {
        int s[8];
#pragma unroll
        for (int u = 0; u < 8; u++) s[u] = eSrc[e + u];
        f16x2 v[8];
#pragma unroll
        for (int u = 0; u < 8; u++)
            v[u] = *reinterpret_cast<const f16x2*>(hs + (long long)s[u] * F + lane * 2);
#pragma unroll
        for (int u = 0; u < 8; u++) {
            acc0 += (float)v[u][0];
            acc1 += (float)v[u][1];
        }
    }
    for (; e < re; e++) {
        int s = eSrc[e];
        f16x2 v = *reinterpret_cast<const f16x2*>(hs + (long long)s * F + lane * 2);
        acc0 += (float)v[0];
        acc1 += (float)v[1];
    }
    float di = dinv[node];
    f16x2 o;
    o[0] = (f16)(acc0 * di);
    o[1] = (f16)(acc1 * di);
    *reinterpret_cast<f16x2*>(out + (long long)node * F + lane * 2) = o;
}

// ---- MFMA node GEMM (Block = 4 waves x 64 nodes) ---------------------------
template <int KTILES, int NTILES, int K, int FOUT, bool POOL>
__global__ __launch_bounds__(256) void k_gemm_mfma(
        const f16* __restrict__ in, const f16* __restrict__ Wb,
        const float* __restrict__ bias, const float* __restrict__ dinv,
        const int* __restrict__ batch, f16* __restrict__ outh,
        float* __restrict__ psum, int n) {
    constexpr int KPAD = KTILES * 32;
    constexpr int KP   = KPAD + 8;
    constexpr int PPR  = KPAD / 2;
    constexpr int NSLOT = 4;

    __shared__ f16 a_lds[64 * KP];
    __shared__ float psum_l[POOL ? NSLOT * FOUT : 1];

    int t = threadIdx.x;
    int node0 = blockIdx.x * 64;

    const f16x2* inp = reinterpret_cast<const f16x2*>(in);
    constexpr int TOTP = 64 * PPR;
    for (int f = t; f < TOTP; f += 256) {
        int node = f / PPR;
        int kp = f - node * PPR;
        f16x2 v = {};
        if (node0 + node < n && kp < K / 2)
            v = inp[(long long)(node0 + node) * (K / 2) + kp];
        *reinterpret_cast<f16x2*>(&a_lds[node * KP + kp * 2]) = v;
    }
    if (POOL) {
        for (int i = t; i < NSLOT * FOUT; i += 256) psum_l[i] = 0.f;
    }
    __syncthreads();

    int w = t >> 6;
    int lane = t & 63;
    int quad = lane >> 4;
    int col = lane & 15;

    f16x8 afr[KTILES];
#pragma unroll
    for (int kt = 0; kt < KTILES; kt++)
        afr[kt] = *reinterpret_cast<const f16x8*>(
            &a_lds[(16 * w + col) * KP + kt * 32 + quad * 8]);

    int nodeC = node0 + 16 * w + quad * 4;
    float dv[4];
    int gb[4];
#pragma unroll
    for (int r = 0; r < 4; r++) {
        int nd = nodeC + r;
        bool valid = nd < n;
        if (POOL) {
            gb[r] = valid ? batch[nd] : -1;
            dv[r] = 0.f;
        } else {
            dv[r] = valid ? dinv[nd] : 0.f;
            gb[r] = -1;
        }
    }
    int g0 = POOL ? batch[node0] : 0;

    const f16x8* wb = reinterpret_cast<const f16x8*>(Wb);
#pragma unroll
    for (int nt = 0; nt < NTILES; nt++) {
        f16x8 bfr[KTILES];
#pragma unroll
        for (int kt = 0; kt < KTILES; kt++)
            bfr[kt] = wb[(nt * KTILES + kt) * 64 + lane];
        f32x4 acc = {0.f, 0.f, 0.f, 0.f};
#pragma unroll
        for (int kt = 0; kt < KTILES; kt++)
            acc = __builtin_amdgcn_mfma_f32_16x16x32_f16(afr[kt], bfr[kt], acc, 0, 0, 0);

        int ch = nt * 16 + col;
        if (ch < FOUT) {
            float bval = bias[ch];
            if (POOL) {
                if (gb[0] == gb[3] && gb[0] >= 0) {
                    float s = fmaxf(acc[0] + bval, 0.f) + fmaxf(acc[1] + bval, 0.f)
                            + fmaxf(acc[2] + bval, 0.f) + fmaxf(acc[3] + bval, 0.f);
                    int slot = gb[0] - g0;
                    if (slot < NSLOT) atomicAdd(&psum_l[slot * FOUT + ch], s);
                    else atomicAdd(&psum[gb[0] * FOUT + ch], s);
                } else {
#pragma unroll
                    for (int r = 0; r < 4; r++) {
                        if (gb[r] < 0) continue;
                        float v = fmaxf(acc[r] + bval, 0.f);
                        int slot = gb[r] - g0;
                        if (slot < NSLOT) atomicAdd(&psum_l[slot * FOUT + ch], v);
                        else atomicAdd(&psum[gb[r] * FOUT + ch], v);
                    }
                }
            } else {
#pragma unroll
                for (int r = 0; r < 4; r++) {
                    int nd = nodeC + r;
                    if (nd < n)
                        outh[(long long)nd * FOUT + ch] =
                            (f16)(fmaxf(acc[r] + bval, 0.f) * dv[r]);
                }
            }
        }
    }

    if (POOL) {
        __syncthreads();
        int lastNode = node0 + 63;
        if (lastNode >= n) lastNode = n - 1;
        int nsl = batch[lastNode] - g0 + 1;
        if (nsl > NSLOT) nsl = NSLOT;
        for (int f = t; f < nsl * FOUT; f += 256) {
            float v = psum_l[f];
            if (v != 0.f) atomicAdd(&psum[(g0 + f / FOUT) * FOUT + (f % FOUT)], v);
        }
    }
}

// ---- FC layers (split; fc1 folds the mean divide) --------------------------
__global__ void k_fc1(const float* __restrict__ P, const int* __restrict__ start,
                      const float* __restrict__ W, const float* __restrict__ bias,
                      float* __restrict__ out) {
    int row = blockIdx.x >> 2;
    int o = (blockIdx.x & 3) * 256 + threadIdx.x;
    int cnt = start[row + 1] - start[row];
    float scale = 1.0f / fmaxf((float)cnt, 1.0f);
    __shared__ float prow[216];
    if (threadIdx.x < 216) prow[threadIdx.x] = P[row * 216 + threadIdx.x] * scale;
    __syncthreads();
    float acc = bias[o];
    for (int k = 0; k < 216; k++) acc += prow[k] * W[k * 1024 + o];
    out[row * 1024 + o] = fmaxf(acc, 0.f);
}
__global__ void k_fc2(const float* __restrict__ G, const float* __restrict__ W,
                      const float* __restrict__ bias, float* __restrict__ out) {
    int row = blockIdx.x;
    int o = threadIdx.x;  // 128
    __shared__ float grow[1024];
    for (int k = threadIdx.x; k < 1024; k += 128) grow[k] = G[row * 1024 + k];
    __syncthreads();
    float acc = bias[o];
    for (int k = 0; k < 1024; k++) acc += grow[k] * W[k * 128 + o];
    out[row * 128 + o] = acc;
}

// ---------------------------------------------------------------------------
extern "C" void kernel_launch(void* const* d_in, const int* in_sizes, int n_in,
                              void* d_out, int out_size, void* d_ws, size_t ws_size,
                              hipStream_t stream) {
    const float* x     = (const float*)d_in[0];
    const int*   ei    = (const int*)d_in[1];
    const int*   batch = (const int*)d_in[2];
    const float* W1  = (const float*)d_in[3];
    const float* b1  = (const float*)d_in[4];
    const float* W2  = (const float*)d_in[5];
    const float* b2  = (const float*)d_in[6];
    const float* W3  = (const float*)d_in[7];
    const float* b3  = (const float*)d_in[8];
    const float* Wf1 = (const float*)d_in[9];
    const float* bf1 = (const float*)d_in[10];
    const float* Wf2 = (const float*)d_in[11];
    const float* bf2 = (const float*)d_in[12];
    float* out = (float*)d_out;

    const int N = in_sizes[0] / 54;   // 100000 (< 2^17 for ebuf packing)
    const int E = in_sizes[1] / 2;    // 1600000
    const int G = 256;
    const int* row = ei;
    const int* col = ei + E;
    const int NB = cdiv(N, BSPAN);    // 196
    const int NBLK_A = cdiv(E, EPB);

    // workspace carve-up (256B aligned)
    char* ws = (char*)d_ws;
    size_t off = 0;
    auto carve = [&](size_t bytes) {
        void* p = ws + off;
        off += (bytes + 255) & ~(size_t)255;
        return p;
    };
    int*   rowptr  = (int*)carve((size_t)(N + 1) * 4);
    int*   bktCnt  = (int*)carve(256 * 4);
    int*   bktCur  = (int*)carve(256 * 4);
    int*   eSrc    = (int*)carve((size_t)E * 4);
    float* dinv    = (float*)carve((size_t)N * 4);
    f16*   xs      = (f16*)carve((size_t)N * 54 * 2);
    f16*   hsbuf   = (f16*)carve((size_t)N * 108 * 2);
    f16*   bufA    = (f16*)carve((size_t)N * 108 * 2);
    unsigned int* ebuf = (unsigned int*)carve((size_t)E * 4);
    float* psum    = (float*)carve((size_t)G * 216 * 4);
    float* gbuf    = (float*)carve((size_t)G * 1024 * 4);
    int*   start   = (int*)carve((size_t)(G + 1) * 4);
    f16*   w1b     = (f16*)carve((size_t)4 * 2 * 512 * 2);
    f16*   w2b     = (f16*)carve((size_t)7 * 2 * 512 * 2);
    f16*   w3b     = (f16*)carve((size_t)14 * 4 * 512 * 2);

    const int T = 256;

    // ---- setup + weight pack + graph boundaries (edge-independent) ----
    k_setup<<<cdiv(G * 216, T), T, 0, stream>>>(psum, G * 216, bktCnt, bktCur);
    k_wpack3<<<cdiv((4 * 2 + 7 * 2 + 14 * 4) * 512, T), T, 0, stream>>>(
        W1, W2, W3, w1b, w2b, w3b);
    k_find_start<<<cdiv(N, T), T, 0, stream>>>(batch, start, N, G);

    // ---- bucketed CSR build: hist -> part -> build ----
    k_bkt_hist<<<NBLK_A, 256, 0, stream>>>(col, bktCnt, E, NB);
    k_bkt_part<<<NBLK_A, 256, 0, stream>>>(row, col, bktCnt, bktCur, ebuf, E, NB);
    k_bkt_build<<<NB, 256, 0, stream>>>(ebuf, bktCnt, rowptr, dinv, eSrc, N, NB);

    // ---- prescale ----
    k_prescale<54><<<cdiv(N * 27, T), T, 0, stream>>>(x, dinv, xs, N);

    const int GB = cdiv(N, 64);

    // ---- layer 1 ----
    k_gather54<<<cdiv(N, 4), 256, 0, stream>>>(rowptr, eSrc, dinv, xs, bufA, N);
    k_gemm_mfma<2, 4, 54, 54, false><<<GB, 256, 0, stream>>>(
        bufA, w1b, b1, dinv, nullptr, hsbuf, nullptr, N);

    // ---- layer 2 ----
    k_gather54<<<cdiv(N, 4), 256, 0, stream>>>(rowptr, eSrc, dinv, hsbuf, bufA, N);
    k_gemm_mfma<2, 7, 54, 108, false><<<GB, 256, 0, stream>>>(
        bufA, w2b, b2, dinv, nullptr, hsbuf, nullptr, N);

    // ---- layer 3 (fused pool) ----
    k_gather<108><<<cdiv(N, 4), 256, 0, stream>>>(rowptr, eSrc, dinv, hsbuf, bufA, N);
    k_gemm_mfma<4, 14, 108, 216, true><<<GB, 256, 0, stream>>>(
        bufA, w3b, b3, nullptr, batch, nullptr, psum, N);

    // ---- FC head (split) ----
    k_fc1<<<G * 4, T, 0, stream>>>(psum, start, Wf1, bf1, gbuf);
    k_fc2<<<G, 128, 0, stream>>>(gbuf, Wf2, bf2, out);
}